// Round 1
// baseline (395.023 us; speedup 1.0000x reference)
//
#include <hip/hip_runtime.h>
#include <stdint.h>

// Problem constants: B=4, C=512, H*W=4096, 32 groups of 16 channels.
#define S_ 4096

typedef __attribute__((ext_vector_type(8))) short short8;
typedef __attribute__((ext_vector_type(4))) float f32x4;

__device__ __forceinline__ short cvt_bf16(float f) {
  uint32_t u = __builtin_bit_cast(uint32_t, f);
  u += 0x7FFFu + ((u >> 16) & 1u);   // RNE
  return (short)(u >> 16);
}

__device__ __forceinline__ void gload_lds16(const void* g, void* l) {
  __builtin_amdgcn_global_load_lds(
      (const __attribute__((address_space(1))) void*)g,
      (__attribute__((address_space(3))) void*)l, 16, 0, 0);
}

// ---------------- weight transpose: src fp32 [512][512] -> dst bf16 [n][c] ----------------
__global__ __launch_bounds__(256) void k_transpose_w(const float* __restrict__ src,
                                                     short* __restrict__ dst) {
  __shared__ float t[32][33];
  int n0 = blockIdx.x * 32, c0 = blockIdx.y * 32;
  int lx = threadIdx.x & 31, ly = threadIdx.x >> 5;
#pragma unroll
  for (int i = 0; i < 4; ++i) {
    int c = ly + i * 8;
    t[c][lx] = src[(size_t)(c0 + c) * 512 + n0 + lx];
  }
  __syncthreads();
#pragma unroll
  for (int i = 0; i < 4; ++i) {
    int n = ly + i * 8;
    dst[(size_t)(n0 + n) * 512 + c0 + lx] = cvt_bf16(t[lx][n]);
  }
}

__global__ void k_bias_concat(const float* __restrict__ bq, const float* __restrict__ bk,
                              float* __restrict__ bqk) {
  int i = blockIdx.x * 256 + threadIdx.x;
  if (i < 512) bqk[i] = bq[i];
  else if (i < 1024) bqk[i] = bk[i - 512];
}

// ---------------- GroupNorm stats: one block per (b,g), 16ch*4096px = 65536 floats ----------------
__global__ __launch_bounds__(256) void k_gn_stats(const float* __restrict__ x,
                                                  float* __restrict__ stats) {
  int bg = blockIdx.x;  // 0..127 ; offset = bg*65536 (groups are contiguous)
  const float* p = x + (size_t)bg * 65536;
  float s = 0.f, ss = 0.f;
#pragma unroll 4
  for (int i = 0; i < 64; ++i) {
    float4 v = *(const float4*)(p + i * 1024 + threadIdx.x * 4);
    s += v.x + v.y + v.z + v.w;
    ss += v.x * v.x + v.y * v.y + v.z * v.z + v.w * v.w;
  }
#pragma unroll
  for (int m = 1; m < 64; m <<= 1) {
    s += __shfl_xor(s, m, 64);
    ss += __shfl_xor(ss, m, 64);
  }
  __shared__ float red[8];
  int w = threadIdx.x >> 6;
  if ((threadIdx.x & 63) == 0) { red[w * 2] = s; red[w * 2 + 1] = ss; }
  __syncthreads();
  if (threadIdx.x == 0) {
    float S1 = red[0] + red[2] + red[4] + red[6];
    float S2 = red[1] + red[3] + red[5] + red[7];
    float mean = S1 * (1.f / 65536.f);
    float var = S2 * (1.f / 65536.f) - mean * mean;
    stats[bg * 2] = mean;
    stats[bg * 2 + 1] = rsqrtf(var + 1e-6f);
  }
}

// ---------------- normalize + transpose: x[b][c][p] fp32 -> h_t[b*4096+p][c] bf16 ----------------
__global__ __launch_bounds__(256) void k_gn_apply(const float* __restrict__ x,
    const float* __restrict__ stats, const float* __restrict__ gsc,
    const float* __restrict__ gbi, short* __restrict__ h_t) {
  __shared__ float t[64][65];
  int p0 = blockIdx.x * 64, c0 = blockIdx.y * 64, b = blockIdx.z;
  int lp = threadIdx.x & 63, lc = threadIdx.x >> 6;
#pragma unroll
  for (int i = 0; i < 16; ++i) {
    int c = c0 + lc * 16 + i;
    float mean = stats[(b * 32 + (c >> 4)) * 2];
    float rstd = stats[(b * 32 + (c >> 4)) * 2 + 1];
    float v = x[((size_t)b * 512 + c) * 4096 + p0 + lp];
    t[lc * 16 + i][lp] = (v - mean) * rstd * gsc[c] + gbi[c];
  }
  __syncthreads();
  int pl = threadIdx.x >> 2;
  int cs = (threadIdx.x & 3) * 16;
  short8 v8a, v8b;
#pragma unroll
  for (int j = 0; j < 8; ++j) v8a[j] = cvt_bf16(t[cs + j][pl]);
#pragma unroll
  for (int j = 0; j < 8; ++j) v8b[j] = cvt_bf16(t[cs + 8 + j][pl]);
  size_t o = ((size_t)(b * 4096 + p0 + pl)) * 512 + c0 + cs;
  *(short8*)(h_t + o) = v8a;
  *(short8*)(h_t + o + 8) = v8b;
}

// ---------------- GEMM: A[M][512] x B[N][512] (both K-major bf16) -> C[M][N] ----------------
// BIAS_M: bias indexed by row (M) instead of col. FINAL: fp32 out + residual, C-layout remap.
template <int BIAS_M, int FINAL>
__global__ __launch_bounds__(256) void k_gemm(const short* __restrict__ A,
    const short* __restrict__ Bm, const float* __restrict__ bias,
    short* __restrict__ Cb, float* __restrict__ Cf, const float* __restrict__ resid,
    int ldc) {
  __shared__ __align__(16) short a_lds[128 * 32];
  __shared__ __align__(16) short b_lds[128 * 32];
  int m0 = blockIdx.x * 128, n0 = blockIdx.y * 128;
  int lane = threadIdx.x & 63, wid = threadIdx.x >> 6;
  int h16 = lane >> 4, l16 = lane & 15;
  int wr = wid >> 1, wc = wid & 1;
  int srow = lane >> 2, sslot = lane & 3;

  f32x4 acc[4][4];
#pragma unroll
  for (int mi = 0; mi < 4; ++mi)
#pragma unroll
    for (int ni = 0; ni < 4; ++ni) acc[mi][ni] = (f32x4){0.f, 0.f, 0.f, 0.f};

  for (int kk = 0; kk < 16; ++kk) {
#pragma unroll
    for (int i = 0; i < 2; ++i) {
      int r0 = (wid * 2 + i) * 16;  // 16 rows per instruction
      gload_lds16(A + ((size_t)(m0 + r0 + srow)) * 512 + kk * 32 + sslot * 8, a_lds + r0 * 32);
      gload_lds16(Bm + ((size_t)(n0 + r0 + srow)) * 512 + kk * 32 + sslot * 8, b_lds + r0 * 32);
    }
    asm volatile("s_waitcnt vmcnt(0)" ::: "memory");
    __syncthreads();
    short8 af[4], bf[4];
#pragma unroll
    for (int mi = 0; mi < 4; ++mi)
      af[mi] = *(const short8*)(a_lds + (wr * 64 + mi * 16 + l16) * 32 + h16 * 8);
#pragma unroll
    for (int ni = 0; ni < 4; ++ni)
      bf[ni] = *(const short8*)(b_lds + (wc * 64 + ni * 16 + l16) * 32 + h16 * 8);
#pragma unroll
    for (int mi = 0; mi < 4; ++mi)
#pragma unroll
      for (int ni = 0; ni < 4; ++ni)
        acc[mi][ni] = __builtin_amdgcn_mfma_f32_16x16x32_bf16(af[mi], bf[ni], acc[mi][ni], 0, 0, 0);
    __syncthreads();
  }

#pragma unroll
  for (int mi = 0; mi < 4; ++mi)
#pragma unroll
    for (int ni = 0; ni < 4; ++ni)
#pragma unroll
      for (int r = 0; r < 4; ++r) {
        int row = m0 + wr * 64 + mi * 16 + 4 * h16 + r;
        int col = n0 + wc * 64 + ni * 16 + l16;
        float v = acc[mi][ni][r] + (BIAS_M ? bias[row] : bias[col]);
        if (FINAL) {
          // row = channel d2 (0..511), col = b*4096 + pixel
          size_t oidx = ((size_t)((col >> 12) * 512 + row)) * 4096 + (col & 4095);
          Cf[oidx] = v + resid[oidx];
        } else {
          Cb[(size_t)row * ldc + col] = cvt_bf16(v);
        }
      }
}

// ---------------- flash attention: Q-tile 64, KV-tile 64, 8 waves (4 row-bands x 2 splits) ----------
__global__ __launch_bounds__(512, 2) void k_flash(const short* __restrict__ qk,
    const short* __restrict__ v_t, short* __restrict__ o_attn) {
  __shared__ __align__(16) short k_lds[64 * 520];   // [p'][512 d] rows padded to 1040B
  __shared__ __align__(16) short v_lds[512 * 64];   // [d][64 p'] XOR-swizzled 16B slots
  __shared__ __align__(16) short p_lds[64 * 72];    // [p][64 p'] rows padded to 144B
  __shared__ float red_m[64][2];
  __shared__ float red_l[64][2];

  int b = blockIdx.y, qt = blockIdx.x;
  int lane = threadIdx.x & 63, wid = threadIdx.x >> 6;
  int h16 = lane >> 4, l16 = lane & 15;
  int wr = wid >> 1, wc = wid & 1;
  const float K2 = 1.4426950408889634f / 22.627416997969522f;  // log2(e)/sqrt(512)

  // Q rows of this wave's 16-row band, all K in registers (A-frags for 16 k-steps)
  const short* qbase = qk + ((size_t)(b * 4096 + qt * 64 + wr * 16 + l16)) * 1024;
  short8 qf[16];
#pragma unroll
  for (int kk = 0; kk < 16; ++kk) qf[kk] = *(const short8*)(qbase + kk * 32 + h16 * 8);

  float m_run[4], l_run[4];
#pragma unroll
  for (int r = 0; r < 4; ++r) { m_run[r] = -3.0e38f; l_run[r] = 0.f; }
  f32x4 oacc[16];
#pragma unroll
  for (int cf = 0; cf < 16; ++cf) oacc[cf] = (f32x4){0.f, 0.f, 0.f, 0.f};

  int vrow_off = lane >> 3;                  // d within 8-row group
  int vslot = (lane & 7) ^ (vrow_off & 7);   // pre-swizzled source 16B slot

  for (int kt = 0; kt < 64; ++kt) {
    int kv0 = kt * 64;
    // stage K tile: rows [p'][512] (k-projection lives at col offset +512 in qk)
#pragma unroll
    for (int rr = 0; rr < 8; ++rr) {
      int row = wid * 8 + rr;
      gload_lds16(qk + ((size_t)(b * 4096 + kv0 + row)) * 1024 + 512 + lane * 8,
                  k_lds + row * 520);
    }
    // stage V tile [d][64 p'], source pre-swizzled so linear LDS dest == swizzled layout
#pragma unroll
    for (int ii = 0; ii < 8; ++ii) {
      int i = wid * 8 + ii;
      int d = i * 8 + vrow_off;
      gload_lds16(v_t + (size_t)d * 16384 + (b * 4096 + kv0) + vslot * 8, v_lds + i * 512);
    }
    asm volatile("s_waitcnt vmcnt(0)" ::: "memory");
    __syncthreads();

    // QK^T: this wave: 16 rows x 32 cols (wc half)
    f32x4 sc[2];
    sc[0] = (f32x4){0.f, 0.f, 0.f, 0.f};
    sc[1] = (f32x4){0.f, 0.f, 0.f, 0.f};
#pragma unroll
    for (int kk = 0; kk < 16; ++kk) {
#pragma unroll
      for (int c = 0; c < 2; ++c) {
        short8 kf = *(const short8*)(k_lds + (wc * 32 + c * 16 + l16) * 520 + kk * 32 + h16 * 8);
        sc[c] = __builtin_amdgcn_mfma_f32_16x16x32_bf16(qf[kk], kf, sc[c], 0, 0, 0);
      }
    }
    // partial row max over this wave's 32 cols
    float mt[4];
#pragma unroll
    for (int r = 0; r < 4; ++r) mt[r] = fmaxf(sc[0][r], sc[1][r]);
#pragma unroll
    for (int m = 1; m < 16; m <<= 1)
#pragma unroll
      for (int r = 0; r < 4; ++r) mt[r] = fmaxf(mt[r], __shfl_xor(mt[r], m, 64));
    if (l16 == 0)
#pragma unroll
      for (int r = 0; r < 4; ++r) red_m[wr * 16 + 4 * h16 + r][wc] = mt[r];
    __syncthreads();

    float mn[4], resc[4], ls[4];
#pragma unroll
    for (int r = 0; r < 4; ++r) {
      int row = wr * 16 + 4 * h16 + r;
      float mfull = fmaxf(red_m[row][0], red_m[row][1]);
      mn[r] = fmaxf(m_run[r], mfull);
      resc[r] = exp2f((m_run[r] - mn[r]) * K2);
      m_run[r] = mn[r];
      ls[r] = 0.f;
    }
    // P = exp(alpha*(s-m)) -> bf16 LDS, partial row sums
#pragma unroll
    for (int c = 0; c < 2; ++c)
#pragma unroll
      for (int r = 0; r < 4; ++r) {
        float p = exp2f((sc[c][r] - mn[r]) * K2);
        ls[r] += p;
        p_lds[(wr * 16 + 4 * h16 + r) * 72 + wc * 32 + c * 16 + l16] = cvt_bf16(p);
      }
#pragma unroll
    for (int m = 1; m < 16; m <<= 1)
#pragma unroll
      for (int r = 0; r < 4; ++r) ls[r] += __shfl_xor(ls[r], m, 64);
    if (l16 == 0)
#pragma unroll
      for (int r = 0; r < 4; ++r) red_l[wr * 16 + 4 * h16 + r][wc] = ls[r];
    __syncthreads();

#pragma unroll
    for (int r = 0; r < 4; ++r) {
      int row = wr * 16 + 4 * h16 + r;
      l_run[r] = l_run[r] * resc[r] + red_l[row][0] + red_l[row][1];
    }
#pragma unroll
    for (int cf = 0; cf < 16; ++cf)
#pragma unroll
      for (int r = 0; r < 4; ++r) oacc[cf][r] *= resc[r];

    // PV: this wave: 16 rows x 256 d (wc half), K=64 over two k-steps
#pragma unroll
    for (int ks = 0; ks < 2; ++ks) {
      short8 pa = *(const short8*)(p_lds + (wr * 16 + l16) * 72 + ks * 32 + h16 * 8);
#pragma unroll
      for (int cf = 0; cf < 16; ++cf) {
        int dcol = wc * 256 + cf * 16 + l16;
        short8 vb = *(const short8*)(v_lds + dcol * 64 + (((ks * 4 + h16) ^ (l16 & 7)) * 8));
        oacc[cf] = __builtin_amdgcn_mfma_f32_16x16x32_bf16(pa, vb, oacc[cf], 0, 0, 0);
      }
    }
    __syncthreads();
  }

  float inv[4];
#pragma unroll
  for (int r = 0; r < 4; ++r) inv[r] = 1.f / l_run[r];
#pragma unroll
  for (int cf = 0; cf < 16; ++cf)
#pragma unroll
    for (int r = 0; r < 4; ++r) {
      int row = b * 4096 + qt * 64 + wr * 16 + 4 * h16 + r;
      int col = wc * 256 + cf * 16 + l16;
      o_attn[(size_t)row * 512 + col] = cvt_bf16(oacc[cf][r] * inv[r]);
    }
}

extern "C" void kernel_launch(void* const* d_in, const int* in_sizes, int n_in,
                              void* d_out, int out_size, void* d_ws, size_t ws_size,
                              hipStream_t stream) {
  const float* x   = (const float*)d_in[0];
  const float* gsc = (const float*)d_in[1];
  const float* gbi = (const float*)d_in[2];
  const float* wq  = (const float*)d_in[3];
  const float* bq  = (const float*)d_in[4];
  const float* wk  = (const float*)d_in[5];
  const float* bk  = (const float*)d_in[6];
  const float* wv  = (const float*)d_in[7];
  const float* bv  = (const float*)d_in[8];
  const float* wo  = (const float*)d_in[9];
  const float* bo  = (const float*)d_in[10];
  float* out = (float*)d_out;

  char* ws = (char*)d_ws;
  float* stats = (float*)ws;                             // 1 KB
  float* bqk   = (float*)(ws + 4096);                    // 4 KB
  short* wqk_t = (short*)(ws + 16384);                   // 1 MB  [1024][512]
  short* wv_t  = (short*)(ws + 16384 + (1u << 20));      // 0.5 MB [512][512]
  short* wo_t  = (short*)(ws + 16384 + (1u << 20) + (1u << 19));
  char*  big   = ws + 16384 + (1u << 21);
  short* h_t   = (short*)big;                            // 16 MB [16384][512]
  short* qkb   = (short*)(big + (16ll << 20));           // 32 MB [16384][1024]
  short* v_t   = (short*)(big + (48ll << 20));           // 16 MB [512][16384]
  short* o_at  = (short*)(big + (64ll << 20));           // 16 MB [16384][512]

  dim3 b256(256);
  k_transpose_w<<<dim3(16, 16), b256, 0, stream>>>(wq, wqk_t);
  k_transpose_w<<<dim3(16, 16), b256, 0, stream>>>(wk, wqk_t + 512 * 512);
  k_transpose_w<<<dim3(16, 16), b256, 0, stream>>>(wv, wv_t);
  k_transpose_w<<<dim3(16, 16), b256, 0, stream>>>(wo, wo_t);
  k_bias_concat<<<4, 256, 0, stream>>>(bq, bk, bqk);
  k_gn_stats<<<128, b256, 0, stream>>>(x, stats);
  k_gn_apply<<<dim3(64, 8, 4), b256, 0, stream>>>(x, stats, gsc, gbi, h_t);
  // Q|K projection: [16384][512] x [1024][512]^T -> qkb[16384][1024], bias over N
  k_gemm<0, 0><<<dim3(128, 8), b256, 0, stream>>>(h_t, wqk_t, bqk, qkb, nullptr, nullptr, 1024);
  // V projection transposed: [512][512] x [16384][512]^T -> v_t[512][16384], bias over M
  k_gemm<1, 0><<<dim3(4, 128), b256, 0, stream>>>(wv_t, h_t, bv, v_t, nullptr, nullptr, 16384);
  // attention
  k_flash<<<dim3(64, 4), dim3(512), 0, stream>>>(qkb, v_t, o_at);
  // output projection transposed + bias + residual -> fp32 out[b][c][hw]
  k_gemm<1, 1><<<dim3(4, 128), b256, 0, stream>>>(wo_t, o_at, bo, nullptr, out, x, 0);
}

// Round 2
// 369.529 us; speedup vs baseline: 1.0690x; 1.0690x over previous
//
#include <hip/hip_runtime.h>
#include <stdint.h>

typedef __attribute__((ext_vector_type(8))) short short8;
typedef __attribute__((ext_vector_type(4))) float f32x4;
typedef __attribute__((ext_vector_type(16))) float f32x16;
typedef __attribute__((ext_vector_type(2))) unsigned int uint2v;

__device__ __forceinline__ short cvt_bf16(float f) {
  uint32_t u = __builtin_bit_cast(uint32_t, f);
  u += 0x7FFFu + ((u >> 16) & 1u);   // RNE
  return (short)(u >> 16);
}

__device__ __forceinline__ float bf16_to_f32(short s) {
  return __builtin_bit_cast(float, (uint32_t)((unsigned short)s) << 16);
}

__device__ __forceinline__ void gload_lds16(const void* g, void* l) {
  __builtin_amdgcn_global_load_lds(
      (const __attribute__((address_space(1))) void*)g,
      (__attribute__((address_space(3))) void*)l, 16, 0, 0);
}

// ---------------- weight transpose: src fp32 [512][512] -> dst bf16 [n][c] ----------------
__global__ __launch_bounds__(256) void k_transpose_w(const float* __restrict__ src,
                                                     short* __restrict__ dst) {
  __shared__ float t[32][33];
  int n0 = blockIdx.x * 32, c0 = blockIdx.y * 32;
  int lx = threadIdx.x & 31, ly = threadIdx.x >> 5;
#pragma unroll
  for (int i = 0; i < 4; ++i) {
    int c = ly + i * 8;
    t[c][lx] = src[(size_t)(c0 + c) * 512 + n0 + lx];
  }
  __syncthreads();
#pragma unroll
  for (int i = 0; i < 4; ++i) {
    int n = ly + i * 8;
    dst[(size_t)(n0 + n) * 512 + c0 + lx] = cvt_bf16(t[lx][n]);
  }
}

__global__ void k_bias_concat(const float* __restrict__ bq, const float* __restrict__ bk,
                              float* __restrict__ bqk) {
  int i = blockIdx.x * 256 + threadIdx.x;
  if (i < 512) bqk[i] = bq[i];
  else if (i < 1024) bqk[i] = bk[i - 512];
}

// ---------------- GroupNorm stats ----------------
__global__ __launch_bounds__(256) void k_gn_stats(const float* __restrict__ x,
                                                  float* __restrict__ stats) {
  int bg = blockIdx.x;
  const float* p = x + (size_t)bg * 65536;
  float s = 0.f, ss = 0.f;
#pragma unroll 4
  for (int i = 0; i < 64; ++i) {
    float4 v = *(const float4*)(p + i * 1024 + threadIdx.x * 4);
    s += v.x + v.y + v.z + v.w;
    ss += v.x * v.x + v.y * v.y + v.z * v.z + v.w * v.w;
  }
#pragma unroll
  for (int m = 1; m < 64; m <<= 1) {
    s += __shfl_xor(s, m, 64);
    ss += __shfl_xor(ss, m, 64);
  }
  __shared__ float red[8];
  int w = threadIdx.x >> 6;
  if ((threadIdx.x & 63) == 0) { red[w * 2] = s; red[w * 2 + 1] = ss; }
  __syncthreads();
  if (threadIdx.x == 0) {
    float S1 = red[0] + red[2] + red[4] + red[6];
    float S2 = red[1] + red[3] + red[5] + red[7];
    float mean = S1 * (1.f / 65536.f);
    float var = S2 * (1.f / 65536.f) - mean * mean;
    stats[bg * 2] = mean;
    stats[bg * 2 + 1] = rsqrtf(var + 1e-6f);
  }
}

// ---------------- normalize + transpose -> h_t[b*4096+p][c] bf16 ----------------
__global__ __launch_bounds__(256) void k_gn_apply(const float* __restrict__ x,
    const float* __restrict__ stats, const float* __restrict__ gsc,
    const float* __restrict__ gbi, short* __restrict__ h_t) {
  __shared__ float t[64][65];
  int p0 = blockIdx.x * 64, c0 = blockIdx.y * 64, b = blockIdx.z;
  int lp = threadIdx.x & 63, lc = threadIdx.x >> 6;
#pragma unroll
  for (int i = 0; i < 16; ++i) {
    int c = c0 + lc * 16 + i;
    float mean = stats[(b * 32 + (c >> 4)) * 2];
    float rstd = stats[(b * 32 + (c >> 4)) * 2 + 1];
    float v = x[((size_t)b * 512 + c) * 4096 + p0 + lp];
    t[lc * 16 + i][lp] = (v - mean) * rstd * gsc[c] + gbi[c];
  }
  __syncthreads();
  int pl = threadIdx.x >> 2;
  int cs = (threadIdx.x & 3) * 16;
  short8 v8a, v8b;
#pragma unroll
  for (int j = 0; j < 8; ++j) v8a[j] = cvt_bf16(t[cs + j][pl]);
#pragma unroll
  for (int j = 0; j < 8; ++j) v8b[j] = cvt_bf16(t[cs + 8 + j][pl]);
  size_t o = ((size_t)(b * 4096 + p0 + pl)) * 512 + c0 + cs;
  *(short8*)(h_t + o) = v8a;
  *(short8*)(h_t + o + 8) = v8b;
}

// ---------------- GEMM: A[M][512] x B[N][512] (K-major bf16) -> C[M][N] ----------------
template <int BIAS_M, int FINAL>
__global__ __launch_bounds__(256) void k_gemm(const short* __restrict__ A,
    const short* __restrict__ Bm, const float* __restrict__ bias,
    short* __restrict__ Cb, float* __restrict__ Cf, const float* __restrict__ resid,
    int ldc) {
  __shared__ __align__(16) short a_lds[128 * 32];
  __shared__ __align__(16) short b_lds[128 * 32];
  int m0 = blockIdx.x * 128, n0 = blockIdx.y * 128;
  int lane = threadIdx.x & 63, wid = threadIdx.x >> 6;
  int h16 = lane >> 4, l16 = lane & 15;
  int wr = wid >> 1, wc = wid & 1;
  int srow = lane >> 2, sslot = lane & 3;

  f32x4 acc[4][4];
#pragma unroll
  for (int mi = 0; mi < 4; ++mi)
#pragma unroll
    for (int ni = 0; ni < 4; ++ni) acc[mi][ni] = (f32x4){0.f, 0.f, 0.f, 0.f};

  for (int kk = 0; kk < 16; ++kk) {
#pragma unroll
    for (int i = 0; i < 2; ++i) {
      int r0 = (wid * 2 + i) * 16;
      gload_lds16(A + ((size_t)(m0 + r0 + srow)) * 512 + kk * 32 + sslot * 8, a_lds + r0 * 32);
      gload_lds16(Bm + ((size_t)(n0 + r0 + srow)) * 512 + kk * 32 + sslot * 8, b_lds + r0 * 32);
    }
    asm volatile("s_waitcnt vmcnt(0)" ::: "memory");
    __syncthreads();
    short8 af[4], bf[4];
#pragma unroll
    for (int mi = 0; mi < 4; ++mi)
      af[mi] = *(const short8*)(a_lds + (wr * 64 + mi * 16 + l16) * 32 + h16 * 8);
#pragma unroll
    for (int ni = 0; ni < 4; ++ni)
      bf[ni] = *(const short8*)(b_lds + (wc * 64 + ni * 16 + l16) * 32 + h16 * 8);
#pragma unroll
    for (int mi = 0; mi < 4; ++mi)
#pragma unroll
      for (int ni = 0; ni < 4; ++ni)
        acc[mi][ni] = __builtin_amdgcn_mfma_f32_16x16x32_bf16(af[mi], bf[ni], acc[mi][ni], 0, 0, 0);
    __syncthreads();
  }

#pragma unroll
  for (int mi = 0; mi < 4; ++mi)
#pragma unroll
    for (int ni = 0; ni < 4; ++ni)
#pragma unroll
      for (int r = 0; r < 4; ++r) {
        int row = m0 + wr * 64 + mi * 16 + 4 * h16 + r;
        int col = n0 + wc * 64 + ni * 16 + l16;
        float v = acc[mi][ni][r] + (BIAS_M ? bias[row] : bias[col]);
        if (FINAL) {
          size_t oidx = ((size_t)((col >> 12) * 512 + row)) * 4096 + (col & 4095);
          Cf[oidx] = v + resid[oidx];
        } else {
          Cb[(size_t)row * ldc + col] = cvt_bf16(v);
        }
      }
}

// ---------------- flash attention v2 ----------------
// QBLK=128, KVBLK=32 (V staged as 64-kv pairs), kv-split=2, 8 waves = 4 qg x 2 dh.
// Swapped QK^T (S^T = mfma(K, Q)), softmax lane-local, 32x32x16 MFMA throughout.
// grid: 256 blocks; blockIdx: combo = bx&7 -> (b = c>>1, s = c&1), qt = bx>>3.
__global__ __launch_bounds__(512, 2) void k_flash2(const short* __restrict__ qk,
    const short* __restrict__ v_t, short* __restrict__ oa, short* __restrict__ ob,
    float* __restrict__ ml) {
  __shared__ __align__(16) short k_lds[32 * 512];   // [32 kv][512 d] xor-swz chunks   32KB
  __shared__ __align__(16) short v_lds[512 * 64];   // [512 d][64 kv] xor-swz chunks   64KB
  __shared__ __align__(16) float s_lds[8 * 1024];   // 8 tiles [4 regquad][64 lane][4] 32KB
  __shared__ __align__(16) short p_lds[128 * 40];   // [128 q][32 kv + pad] (80B rows) 10KB

  const int tid = threadIdx.x;
  const int lane = tid & 63, wid = tid >> 6;
  const int qg = wid >> 1, dh = wid & 1;
  const int l31 = lane & 31, h = lane >> 5;
  const int bx = blockIdx.x;
  const int combo = bx & 7, qt = bx >> 3;
  const int b = combo >> 1, s = combo & 1;
  const float K2 = 0.06376649f;  // log2(e)/sqrt(512)

  // Q B-frags: 32 q-cols (qg), 256 d (dh), 16 ksteps of K=16
  short8 qf[16];
  {
    const short* qbase = qk + ((size_t)(b * 4096 + qt * 128 + qg * 32 + l31)) * 1024
                         + dh * 256 + h * 8;
#pragma unroll
    for (int ks = 0; ks < 16; ++ks) qf[ks] = *(const short8*)(qbase + ks * 16);
  }
  asm volatile("s_waitcnt vmcnt(0)" ::: "memory");

  const size_t kvrow0 = (size_t)(b * 4096 + s * 2048);

  // stage K tile t (32 rows x 512 d): 4 instr/wave, pre-swizzled source
#define STAGE_K(T)                                                                    \
  {                                                                                   \
    int t_ = (T);                                                                     \
    _Pragma("unroll") for (int i = 0; i < 4; ++i) {                                   \
      int row = wid * 4 + i;                                                          \
      gload_lds16(qk + (kvrow0 + t_ * 32 + row) * 1024 + 512 + ((lane ^ (row & 7)) * 8), \
                  k_lds + row * 512);                                                 \
    }                                                                                 \
  }
  // stage V pair p (512 d x 64 kv): 8 instr/wave, pre-swizzled source
#define STAGE_V(P)                                                                    \
  {                                                                                   \
    int p_ = (P);                                                                     \
    _Pragma("unroll") for (int ii = 0; ii < 8; ++ii) {                                \
      int d = wid * 64 + ii * 8 + (lane >> 3);                                        \
      gload_lds16(v_t + (size_t)d * 16384 + (b * 4096 + s * 2048 + p_ * 64)           \
                      + (((lane & 7) ^ (d & 7)) * 8),                                 \
                  v_lds + (wid * 8 + ii) * 512);                                      \
    }                                                                                 \
  }

  STAGE_K(0);
  STAGE_V(0);
  asm volatile("s_waitcnt vmcnt(8)" ::: "memory");  // K0 done, V0 in flight
  __builtin_amdgcn_s_barrier();
  __builtin_amdgcn_sched_barrier(0);

  float m_run = -3.0e38f, l_run = 0.f;
  f32x16 acc[8];
#pragma unroll
  for (int tl = 0; tl < 8; ++tl)
#pragma unroll
    for (int r = 0; r < 16; ++r) acc[tl][r] = 0.f;

  for (int t = 0; t < 64; ++t) {
    // ---- QK^T partial: S^T [32 kv][32 q] over dh's 256 d
    f32x16 st;
#pragma unroll
    for (int r = 0; r < 16; ++r) st[r] = 0.f;
#pragma unroll
    for (int ks = 0; ks < 16; ++ks) {
      int c = dh * 32 + ks * 2 + h;
      short8 kf = *(const short8*)(k_lds + l31 * 512 + ((c ^ (l31 & 7)) * 8));
      st = __builtin_amdgcn_mfma_f32_32x32x16_bf16(kf, qf[ks], st, 0, 0, 0);
    }
    // write own partial: tile[wid], layout [regquad][lane][4] -> conflict-free
    {
      float* sp = s_lds + wid * 1024 + lane * 4;
#pragma unroll
      for (int q4 = 0; q4 < 4; ++q4) {
        f32x4 v = {st[q4 * 4 + 0], st[q4 * 4 + 1], st[q4 * 4 + 2], st[q4 * 4 + 3]};
        *(f32x4*)(sp + q4 * 256) = v;
      }
    }
    asm volatile("s_waitcnt lgkmcnt(0)" ::: "memory");
    __builtin_amdgcn_s_barrier();                    // B1: K reads + S writes done
    __builtin_amdgcn_sched_barrier(0);
    STAGE_K(t + 1 < 64 ? t + 1 : 63);                // overwrite K, lands by B3
    // combine with partner (dh^1) partial
    {
      const float* sp = s_lds + (wid ^ 1) * 1024 + lane * 4;
#pragma unroll
      for (int q4 = 0; q4 < 4; ++q4) {
        f32x4 v = *(const f32x4*)(sp + q4 * 256);
        st[q4 * 4 + 0] += v[0]; st[q4 * 4 + 1] += v[1];
        st[q4 * 4 + 2] += v[2]; st[q4 * 4 + 3] += v[3];
      }
    }
    // ---- softmax: per q-col (= per lane)
    float mt = st[0];
#pragma unroll
    for (int r = 1; r < 16; ++r) mt = fmaxf(mt, st[r]);
    mt = fmaxf(mt, __shfl_xor(mt, 32));
    if (__any(mt > m_run + 45.0f)) {                 // deferred-max rescale (rare)
      float mnew = fmaxf(m_run, mt);
      float rs = exp2f((m_run - mnew) * K2);
      m_run = mnew;
      l_run *= rs;
#pragma unroll
      for (int r = 0; r < 16; ++r) {
        int rowq = (r & 3) + 8 * (r >> 2) + 4 * h;
        float rr = __shfl(rs, rowq);
#pragma unroll
        for (int tl = 0; tl < 8; ++tl) acc[tl][r] *= rr;
      }
    }
    float ls = 0.f;
#pragma unroll
    for (int r = 0; r < 16; ++r) { st[r] = exp2f((st[r] - m_run) * K2); ls += st[r]; }
    ls += __shfl_xor(ls, 32);
    l_run += ls;
    if (dh == 0) {                                   // P -> LDS (bf16), 4x b64/lane
      int q = qg * 32 + l31;
#pragma unroll
      for (int g = 0; g < 4; ++g) {
        unsigned int p0, p1;
        asm("v_cvt_pk_bf16_f32 %0, %1, %2" : "=v"(p0) : "v"(st[4 * g + 0]), "v"(st[4 * g + 1]));
        asm("v_cvt_pk_bf16_f32 %0, %1, %2" : "=v"(p1) : "v"(st[4 * g + 2]), "v"(st[4 * g + 3]));
        uint2v w; w[0] = p0; w[1] = p1;
        *(uint2v*)(p_lds + q * 40 + g * 8 + h * 4) = w;
      }
    }
    asm volatile("s_waitcnt vmcnt(4) lgkmcnt(0)" ::: "memory");  // V ready, K still flying
    __builtin_amdgcn_s_barrier();                    // B2: P visible, V visible
    __builtin_amdgcn_sched_barrier(0);
    // ---- PV: A = P[qg's 32 q][32 kv], B = V[32 kv][dh's 256 d]
#pragma unroll
    for (int ks = 0; ks < 2; ++ks) {
      short8 pa = *(const short8*)(p_lds + (qg * 32 + l31) * 40 + ks * 16 + h * 8);
#pragma unroll
      for (int tl = 0; tl < 8; ++tl) {
        int d = dh * 256 + tl * 32 + l31;
        int c = (t & 1) * 4 + ks * 2 + h;
        short8 vb = *(const short8*)(v_lds + d * 64 + ((c ^ (d & 7)) * 8));
        acc[tl] = __builtin_amdgcn_mfma_f32_32x32x16_bf16(pa, vb, acc[tl], 0, 0, 0);
      }
    }
    asm volatile("s_waitcnt vmcnt(0) lgkmcnt(0)" ::: "memory");  // K next visible; LDS reads done
    __builtin_amdgcn_s_barrier();                    // B3
    __builtin_amdgcn_sched_barrier(0);
    if (t & 1) STAGE_V(((t + 1) >> 1) < 32 ? ((t + 1) >> 1) : 31);
  }

  // epilogue: normalized bf16 partial + (m, l)
  float linv = 1.0f / l_run;
  short* obuf = (s == 0) ? oa : ob;
#pragma unroll
  for (int r = 0; r < 16; ++r) {
    int rowq = (r & 3) + 8 * (r >> 2) + 4 * h;
    float li = __shfl(linv, rowq);
    size_t grow = ((size_t)(b * 4096 + qt * 128 + qg * 32 + rowq)) * 512;
#pragma unroll
    for (int tl = 0; tl < 8; ++tl)
      obuf[grow + dh * 256 + tl * 32 + l31] = cvt_bf16(acc[tl][r] * li);
  }
  if (dh == 0 && lane < 32) {
    int gq = b * 4096 + qt * 128 + qg * 32 + lane;
    ml[((size_t)s * 16384 + gq) * 2 + 0] = m_run;
    ml[((size_t)s * 16384 + gq) * 2 + 1] = l_run;
  }
#undef STAGE_K
#undef STAGE_V
}

// ---------------- combine the two kv-split partials -> o_at (in place over Ob) ----------------
__global__ __launch_bounds__(256) void k_combine(const short* __restrict__ oa,
    const float* __restrict__ ml, short* __restrict__ ob_out) {
  int gq = blockIdx.x * 4 + (threadIdx.x >> 6);
  int d0 = (threadIdx.x & 63) * 8;
  const float K2 = 0.06376649f;
  float ma = ml[(size_t)gq * 2 + 0], la = ml[(size_t)gq * 2 + 1];
  float mb = ml[((size_t)16384 + gq) * 2 + 0], lb = ml[((size_t)16384 + gq) * 2 + 1];
  float m = fmaxf(ma, mb);
  float ca = exp2f((ma - m) * K2) * la;
  float cb = exp2f((mb - m) * K2) * lb;
  float inv = 1.f / (ca + cb);
  ca *= inv; cb *= inv;
  short8 a = *(const short8*)(oa + (size_t)gq * 512 + d0);
  short8 bv = *(const short8*)(ob_out + (size_t)gq * 512 + d0);
  short8 o;
#pragma unroll
  for (int j = 0; j < 8; ++j)
    o[j] = cvt_bf16(ca * bf16_to_f32(a[j]) + cb * bf16_to_f32(bv[j]));
  *(short8*)(ob_out + (size_t)gq * 512 + d0) = o;
}

extern "C" void kernel_launch(void* const* d_in, const int* in_sizes, int n_in,
                              void* d_out, int out_size, void* d_ws, size_t ws_size,
                              hipStream_t stream) {
  const float* x   = (const float*)d_in[0];
  const float* gsc = (const float*)d_in[1];
  const float* gbi = (const float*)d_in[2];
  const float* wq  = (const float*)d_in[3];
  const float* bq  = (const float*)d_in[4];
  const float* wk  = (const float*)d_in[5];
  const float* bk  = (const float*)d_in[6];
  const float* wv  = (const float*)d_in[7];
  const float* bv  = (const float*)d_in[8];
  const float* wo  = (const float*)d_in[9];
  const float* bo  = (const float*)d_in[10];
  float* out = (float*)d_out;

  char* ws = (char*)d_ws;
  float* stats = (float*)ws;                             // 1 KB
  float* bqk   = (float*)(ws + 4096);                    // 4 KB
  short* wqk_t = (short*)(ws + 16384);                   // 1 MB  [1024][512]
  short* wv_t  = (short*)(ws + 16384 + (1u << 20));      // 0.5 MB
  short* wo_t  = (short*)(ws + 16384 + (1u << 20) + (1u << 19));
  char*  big   = ws + 16384 + (1u << 21);
  short* h_t   = (short*)big;                            // 16 MB [16384][512]; reused as Oa
  short* qkb   = (short*)(big + (16ll << 20));           // 32 MB [16384][1024]
  short* v_t   = (short*)(big + (48ll << 20));           // 16 MB [512][16384]
  short* o_at  = (short*)(big + (64ll << 20));           // 16 MB [16384][512]; Ob then final
  float* mlbuf = (float*)(big + (80ll << 20));           // 256 KB [2][16384][2]

  dim3 b256(256);
  k_transpose_w<<<dim3(16, 16), b256, 0, stream>>>(wq, wqk_t);
  k_transpose_w<<<dim3(16, 16), b256, 0, stream>>>(wk, wqk_t + 512 * 512);
  k_transpose_w<<<dim3(16, 16), b256, 0, stream>>>(wv, wv_t);
  k_transpose_w<<<dim3(16, 16), b256, 0, stream>>>(wo, wo_t);
  k_bias_concat<<<4, 256, 0, stream>>>(bq, bk, bqk);
  k_gn_stats<<<128, b256, 0, stream>>>(x, stats);
  k_gn_apply<<<dim3(64, 8, 4), b256, 0, stream>>>(x, stats, gsc, gbi, h_t);
  // Q|K projection -> qkb[16384][1024]
  k_gemm<0, 0><<<dim3(128, 8), b256, 0, stream>>>(h_t, wqk_t, bqk, qkb, nullptr, nullptr, 1024);
  // V projection transposed -> v_t[512][16384]
  k_gemm<1, 0><<<dim3(4, 128), b256, 0, stream>>>(wv_t, h_t, bv, v_t, nullptr, nullptr, 16384);
  // flash attention (h_t now dead -> Oa; o_at holds Ob)
  k_flash2<<<dim3(256), dim3(512), 0, stream>>>(qkb, v_t, h_t, o_at, mlbuf);
  k_combine<<<dim3(4096), b256, 0, stream>>>(h_t, mlbuf, o_at);
  // output projection transposed + bias + residual -> fp32 out
  k_gemm<1, 1><<<dim3(4, 128), b256, 0, stream>>>(wo_t, o_at, bo, nullptr, out, x, 0);
}